// Round 6
// baseline (449.576 us; speedup 1.0000x reference)
//
#include <hip/hip_runtime.h>
#include <math.h>
#include <stdint.h>

// ---------------------------------------------------------------------------
// KAN forward, split-bf16 MFMA version, round 9: phase-staggered waves.
//   R7 structure restored (R8's counted-vmcnt double-barrier regressed:
//   fencing the MFMA cluster blocked cross-wave build/MFMA overlap).
//   512 thr / 8 waves / 128 rows, split-K chunk parity, one __syncthreads
//   per pair, LDS 128 KB double pair-buffer, 32x32x16.
//   NEW: co-SIMD waves (ks=0 / ks=1) run OPPOSITE phase orders per pair:
//     ks=0: [build next frags] -> [MFMA cluster]
//     ks=1: [MFMA cluster] -> [build next frags]
//   so on every SIMD one wave feeds the matrix pipe while the partner does
//   VALU builds, breaking the post-barrier lockstep that left the two pipes
//   strictly additive (R7: MFMA 38% + VALU 42% + stall 20% = 100%).
//   Augmented-K GEMM per layer: K = 9F (8 spline bases + 1 silu per feature).
//   W prefolded, split into bf16 hi/lo pair, staged via global_load_lds.
//   3-product split emulation: Ah*Wh + Al*Wh + Ah*Wl  (error ~2^-16 rel).
// ---------------------------------------------------------------------------

#define N_PTS 32768

using short8 = __attribute__((ext_vector_type(8))) short;
using f32x4  = __attribute__((ext_vector_type(4))) float;
using f32x16 = __attribute__((ext_vector_type(16))) float;

union Frag { short8 v; uint32_t u[4]; };

__device__ __forceinline__ uint32_t bf16rne(float f) {
    uint32_t u = __float_as_uint(f);
    return (u + 0x7FFFu + ((u >> 16) & 1u)) >> 16;
}
__device__ __forceinline__ float bf16tof(uint32_t h) { return __uint_as_float(h << 16); }

// pack bf16-trunc(x0) into lo16, bf16-trunc(x1) into hi16 — one v_perm_b32
__device__ __forceinline__ uint32_t pkhi(uint32_t x0, uint32_t x1) {
    return __builtin_amdgcn_perm(x1, x0, 0x07060302u);
}

// async global->LDS, 16B per lane (wave-uniform base + lane*16 semantics)
__device__ __forceinline__ void gld16(const void* g, void* lds) {
    __builtin_amdgcn_global_load_lds(
        (const __attribute__((address_space(1))) void*)(uintptr_t)g,
        (__attribute__((address_space(3))) void*)(uint32_t)(uintptr_t)lds,
        16, 0, 0);
}

// ---------------------------------------------------------------------------
// fast uniform cubic B-spline, trunc-split bf16 fragments.
// t = (x+2.2)/0.4 ; i = floor(t) ; slot j nonzero for j = i-3..i with value
// q_{i-j}.  Pair p (slots 2p,2p+1) selected from 5 packed candidates by i-2p.
__device__ __forceinline__ void build_basis_frag(float x, Frag& ah, Frag& al) {
    float t  = (x + 2.2f) * 2.5f;
    float fl = floorf(t);
    int   i  = (int)fl;
    float w  = t - fl;
    float w2 = w * w, w3 = w2 * w;
    const float s = 1.0f / 6.0f;
    float q0 = w3 * s;                                     // d == 0 (j == i)
    float q1 = (-3.f * w3 + 3.f * w2 + 3.f * w + 1.f) * s; // d == 1
    float q2 = (3.f * w3 - 6.f * w2 + 4.f) * s;            // d == 2
    float omw = 1.f - w;
    float q3 = omw * omw * omw * s;                        // d == 3
    uint32_t u0 = __float_as_uint(q0), u1 = __float_as_uint(q1);
    uint32_t u2 = __float_as_uint(q2), u3 = __float_as_uint(q3);
    // exact residual of the truncated head, then bf16-trunc via perm
    uint32_t r0 = __float_as_uint(q0 - __uint_as_float(u0 & 0xFFFF0000u));
    uint32_t r1 = __float_as_uint(q1 - __uint_as_float(u1 & 0xFFFF0000u));
    uint32_t r2 = __float_as_uint(q2 - __uint_as_float(u2 & 0xFFFF0000u));
    uint32_t r3 = __float_as_uint(q3 - __uint_as_float(u3 & 0xFFFF0000u));
    uint32_t PH0 = pkhi(u0, 0u), PH1 = pkhi(u1, u0), PH2 = pkhi(u2, u1),
             PH3 = pkhi(u3, u2), PH4 = pkhi(0u, u3);
    uint32_t PL0 = pkhi(r0, 0u), PL1 = pkhi(r1, r0), PL2 = pkhi(r2, r1),
             PL3 = pkhi(r3, r2), PL4 = pkhi(0u, r3);
#pragma unroll
    for (int p = 0; p < 4; ++p) {
        bool c0 = (i == 2 * p), c1 = (i == 2 * p + 1), c2 = (i == 2 * p + 2),
             c3 = (i == 2 * p + 3), c4 = (i == 2 * p + 4);
        ah.u[p] = c0 ? PH0 : c1 ? PH1 : c2 ? PH2 : c3 ? PH3 : c4 ? PH4 : 0u;
        al.u[p] = c0 ? PL0 : c1 ? PL1 : c2 ? PL2 : c3 ? PL3 : c4 ? PL4 : 0u;
    }
}

// silu fragment from 8 prefetched floats (one k-half)
__device__ __forceinline__ void build_silu_frag_v(float4 a, float4 b, Frag& ah, Frag& al) {
    float xs[8] = {a.x, a.y, a.z, a.w, b.x, b.y, b.z, b.w};
#pragma unroll
    for (int p = 0; p < 4; ++p) {
        float x0 = xs[p * 2], x1 = xs[p * 2 + 1];
        float v0 = x0 / (1.f + __expf(-x0));
        float v1 = x1 / (1.f + __expf(-x1));
        uint32_t w0 = __float_as_uint(v0), w1 = __float_as_uint(v1);
        uint32_t l0 = __float_as_uint(v0 - __uint_as_float(w0 & 0xFFFF0000u));
        uint32_t l1 = __float_as_uint(v1 - __uint_as_float(w1 & 0xFFFF0000u));
        ah.u[p] = pkhi(w0, w1);
        al.u[p] = pkhi(l0, l1);
    }
}

// ---------------------------------------------------------------------------
__global__ void encode_kernel(const float* __restrict__ x,
                              const float* __restrict__ freq,
                              float* __restrict__ h0) {
    int n = blockIdx.x * blockDim.x + threadIdx.x;
    if (n >= N_PTS) return;
    float xv = x[n];
#pragma unroll
    for (int l = 0; l < 16; ++l) {
        float e = xv * freq[l];
        h0[n * 32 + l]      = sinf(e);
        h0[n * 32 + 16 + l] = cosf(e);
    }
}

// Fold sw*ss (k = f*8+j) and bw (k = 8F+f) into split-bf16 pair, layout
// Wh/Wl[(k>>3)][col][k&7] so fragment reads are ds_read_b128-contiguous and
// chunk staging (32 k x 256 cols = 16 KB) is flat-contiguous.
__global__ void prep_kernel(const float* __restrict__ bw,
                            const float* __restrict__ sw,
                            const float* __restrict__ ss,
                            short* __restrict__ Wh, short* __restrict__ Wl, int F) {
    int id = blockIdx.x * blockDim.x + threadIdx.x;
    int K = 9 * F;
    if (id >= K * 256) return;
    int col = id & 255;
    int k   = id >> 8;
    float wv;
    if (k < 8 * F) {
        int f = k >> 3, j = k & 7;
        wv = sw[(col * F + f) * 8 + j] * ss[col * F + f];
    } else {
        int f = k - 8 * F;
        wv = bw[col * F + f];
    }
    uint32_t hh = bf16rne(wv);
    uint32_t ll = bf16rne(wv - bf16tof(hh));
    size_t idx = ((size_t)(k >> 3) * 256 + col) * 8 + (k & 7);
    Wh[idx] = (short)hh;
    Wl[idx] = (short)ll;
}

// ---------------------------------------------------------------------------
// out(N,256) = Aug(h)(N,9F) @ W(9F,256), split-bf16 32x32x16 MFMA, split-K,
// phase-staggered waves. Wave (rg, ks): 32 rows, chunks c with c%2==ks.
// A-frag layout (32x32x16): row = lane&31, k = (lane>>5)*8 + j.
// B-frag layout:            col = lane&31, k = (lane>>5)*8 + j.
// C/D layout:               col = lane&31, row = (reg&3)+8*(reg>>2)+4*(lane>>5).
template <int F>
__global__ __launch_bounds__(512, 2)
void layer_mfma(const float* __restrict__ hin,
                const short* __restrict__ Wh, const short* __restrict__ Wl,
                float* __restrict__ out) {
    constexpr int KBC = F / 4;         // basis chunks (8F/32)
    constexpr int KSC = F / 32;        // silu chunks
    constexpr int NC  = KBC + KSC;
    constexpr int NP  = (NC + 1) / 2;  // chunk pairs (last may be singleton)
    __shared__ short WB[2][2][2][8192];   // [pairbuf][cip][h/l][32k x 256col] = 128 KB

    const int tid  = threadIdx.x;
    const int wv   = tid >> 6;
    const int rg   = wv & 3;           // row-group 0..3
    const int ks   = wv >> 2;          // chunk parity 0..1 (SIMD s hosts wv=s and wv=s+4)
    const int lane = tid & 63;
    const int lc   = lane & 31;        // A row / B col within tile
    const int half = lane >> 5;        // k-subgroup
    const int row0 = blockIdx.x * 128;
    const int r    = row0 + rg * 32 + lc;   // this lane's A row
    const float* hrow = hin + (size_t)r * F;

    f32x16 acc[8];
#pragma unroll
    for (int a = 0; a < 8; ++a)
#pragma unroll
        for (int e = 0; e < 16; ++e) acc[a][e] = 0.f;

    auto stage_pair = [&](int p, int buf) {
#pragma unroll
        for (int cip = 0; cip < 2; ++cip) {
            int c = 2 * p + cip;
            if (c < NC) {
                const size_t gof = (size_t)c * 8192;
#pragma unroll
                for (int i = 0; i < 2; ++i) {
                    int e = tid * 8 + i * 4096;
                    gld16(Wh + gof + e, &WB[buf][cip][0][e]);
                    gld16(Wl + gof + e, &WB[buf][cip][1][e]);
                }
            }
        }
    };

    // stage chunk-pair 0 into buf 0
    stage_pair(0, 0);

    // prologue: build frags for first chunk c0 = ks (always basis, KBC >= 8),
    // and prefetch basis inputs for chunk c0+2 (also always basis).
    Frag cah[2], cal[2];
    {
        float x0 = hrow[ks * 4 + half];
        float x1 = hrow[ks * 4 + 2 + half];
        build_basis_frag(x0, cah[0], cal[0]);
        build_basis_frag(x1, cah[1], cal[1]);
    }
    float cinx0 = hrow[(ks + 2) * 4 + half];
    float cinx1 = hrow[(ks + 2) * 4 + 2 + half];
    __syncthreads();

    for (int p = 0; p < NP; ++p) {
        const int cur = p & 1;
        if (p + 1 < NP) stage_pair(p + 1, cur ^ 1);

        const int c  = 2 * p + ks;     // chunk computed this pair
        const int cn = c + 2;          // chunk built this pair
        const int cf = c + 4;          // chunk whose basis inputs we prefetch
        const bool bn = (cn < KBC);
        const bool sn = (cn >= KBC) && (cn < NC);

        // prefetch basis inputs for cf (consumed next pair)
        float ninx0 = 0.f, ninx1 = 0.f;
        if (cf < KBC) {
            ninx0 = hrow[cf * 4 + half];
            ninx1 = hrow[cf * 4 + 2 + half];
        }
        // silu inputs for cn (rare chunks; loaded early for latency)
        float4 s0, s1, s2, s3;
        if (sn) {
            const float* sp = hrow + (cn - KBC) * 32 + half * 8;
            s0 = *(const float4*)sp;
            s1 = *(const float4*)(sp + 4);
            s2 = *(const float4*)(sp + 16);
            s3 = *(const float4*)(sp + 20);
        }

        const short* WHp = WB[cur][ks][0];
        const short* WLp = WB[cur][ks][1];

        auto do_build = [&](Frag* nah, Frag* nal) {
            if (bn) {
                build_basis_frag(cinx0, nah[0], nal[0]);
                build_basis_frag(cinx1, nah[1], nal[1]);
            } else if (sn) {
                build_silu_frag_v(s0, s1, nah[0], nal[0]);
                build_silu_frag_v(s2, s3, nah[1], nal[1]);
            }
        };
        auto do_mfma = [&]() {
#pragma unroll
            for (int ct = 0; ct < 8; ++ct) {
#pragma unroll
                for (int kh = 0; kh < 2; ++kh) {
                    int off = ((kh * 2 + half) * 256 + ct * 32 + lc) * 8;
                    Frag wh, wl;
                    wh.v = *(const short8*)&WHp[off];
                    wl.v = *(const short8*)&WLp[off];
                    acc[ct] = __builtin_amdgcn_mfma_f32_32x32x16_bf16(cah[kh].v, wh.v, acc[ct], 0, 0, 0);
                    acc[ct] = __builtin_amdgcn_mfma_f32_32x32x16_bf16(cal[kh].v, wh.v, acc[ct], 0, 0, 0);
                    acc[ct] = __builtin_amdgcn_mfma_f32_32x32x16_bf16(cah[kh].v, wl.v, acc[ct], 0, 0, 0);
                }
            }
        };

        // ---- staggered phases: ks=0 builds first, ks=1 MFMAs first ----
        Frag nah[2], nal[2];
        if (ks == 0) {
            do_build(nah, nal);
            __builtin_amdgcn_sched_barrier(0);
            if (c < NC) do_mfma();
        } else {
            if (c < NC) do_mfma();
            __builtin_amdgcn_sched_barrier(0);
            do_build(nah, nal);
        }
        __syncthreads();

        // rotate pipeline state
        if (bn || sn) {
            cah[0] = nah[0]; cah[1] = nah[1];
            cal[0] = nal[0]; cal[1] = nal[1];
        }
        if (cf < KBC) { cinx0 = ninx0; cinx1 = ninx1; }
    }

    // ---- cross-ks reduction via LDS (WB reused as 32K-float scratch) ----
    // Tile (rg, ks, cti) = 1024 floats at ((rg*2+ks)*4+cti)*1024; within:
    // e4*256 + lane*4 (contiguous 16B/lane — conflict-free b128 pattern).
    // Wave (rg, ks) writes its partials for the OTHER half's col-tiles, then
    // reads partner's partials for its OWN half, adds, stores to global.
    float* red = (float*)WB;
    {
        float* wp = red + (size_t)((rg * 2 + ks) * 4) * 1024 + lane * 4;
        if (ks == 0) {
#pragma unroll
            for (int cti = 0; cti < 4; ++cti)
#pragma unroll
                for (int e4 = 0; e4 < 4; ++e4) {
                    f32x4 v = {acc[4 + cti][e4 * 4 + 0], acc[4 + cti][e4 * 4 + 1],
                               acc[4 + cti][e4 * 4 + 2], acc[4 + cti][e4 * 4 + 3]};
                    *(f32x4*)(wp + cti * 1024 + e4 * 256) = v;
                }
        } else {
#pragma unroll
            for (int cti = 0; cti < 4; ++cti)
#pragma unroll
                for (int e4 = 0; e4 < 4; ++e4) {
                    f32x4 v = {acc[cti][e4 * 4 + 0], acc[cti][e4 * 4 + 1],
                               acc[cti][e4 * 4 + 2], acc[cti][e4 * 4 + 3]};
                    *(f32x4*)(wp + cti * 1024 + e4 * 256) = v;
                }
        }
    }
    __syncthreads();
    {
        const float* rp = red + (size_t)((rg * 2 + (1 - ks)) * 4) * 1024 + lane * 4;
        if (ks == 0) {
#pragma unroll
            for (int cti = 0; cti < 4; ++cti) {
                const int colg = cti * 32 + lc;
#pragma unroll
                for (int e4 = 0; e4 < 4; ++e4) {
                    f32x4 v = *(const f32x4*)(rp + cti * 1024 + e4 * 256);
#pragma unroll
                    for (int j = 0; j < 4; ++j) {
                        const int rgi  = e4 * 4 + j;
                        const int rowg = row0 + rg * 32 + (rgi & 3) + 8 * (rgi >> 2) + 4 * half;
                        out[(size_t)rowg * 256 + colg] = acc[cti][rgi] + v[j];
                    }
                }
            }
        } else {
#pragma unroll
            for (int cti = 0; cti < 4; ++cti) {
                const int colg = (4 + cti) * 32 + lc;
#pragma unroll
                for (int e4 = 0; e4 < 4; ++e4) {
                    f32x4 v = *(const f32x4*)(rp + cti * 1024 + e4 * 256);
#pragma unroll
                    for (int j = 0; j < 4; ++j) {
                        const int rgi  = e4 * 4 + j;
                        const int rowg = row0 + rg * 32 + (rgi & 3) + 8 * (rgi >> 2) + 4 * half;
                        out[(size_t)rowg * 256 + colg] = acc[4 + cti][rgi] + v[j];
                    }
                }
            }
        }
    }
}

// ---------------------------------------------------------------------------
// Final layer (n_out=1), fp32 wave-reduce.
__device__ __forceinline__ float knotf(int j) { return (float)(j - 3) * 0.4f - 1.0f; }

__device__ __forceinline__ void spline8(float x, float b[8]) {
    float b0[11];
#pragma unroll
    for (int j = 0; j < 11; ++j)
        b0[j] = (x >= knotf(j) && x < knotf(j + 1)) ? 1.0f : 0.0f;
    float b1[10];
#pragma unroll
    for (int j = 0; j < 10; ++j)
        b1[j] = (x - knotf(j)) * (1.0f / (knotf(j + 1) - knotf(j))) * b0[j]
              + (knotf(j + 2) - x) * (1.0f / (knotf(j + 2) - knotf(j + 1))) * b0[j + 1];
    float b2[9];
#pragma unroll
    for (int j = 0; j < 9; ++j)
        b2[j] = (x - knotf(j)) * (1.0f / (knotf(j + 2) - knotf(j))) * b1[j]
              + (knotf(j + 3) - x) * (1.0f / (knotf(j + 3) - knotf(j + 1))) * b1[j + 1];
#pragma unroll
    for (int j = 0; j < 8; ++j)
        b[j]  = (x - knotf(j)) * (1.0f / (knotf(j + 3) - knotf(j))) * b2[j]
              + (knotf(j + 4) - x) * (1.0f / (knotf(j + 4) - knotf(j + 1))) * b2[j + 1];
}

__global__ void layer3_kernel(const float* __restrict__ hin,
                              const float* __restrict__ sw,
                              const float* __restrict__ ss,
                              const float* __restrict__ bw,
                              float* __restrict__ out) {
    int gid  = blockIdx.x * blockDim.x + threadIdx.x;
    int row  = gid >> 6;
    int lane = gid & 63;
    if (row >= N_PTS) return;
    float acc = 0.0f;
#pragma unroll
    for (int it = 0; it < 4; ++it) {
        int f = lane + it * 64;
        float x = hin[(size_t)row * 256 + f];
        float b[8];
        spline8(x, b);
        float dot = 0.0f;
#pragma unroll
        for (int j = 0; j < 8; ++j) dot = fmaf(b[j], sw[f * 8 + j], dot);
        acc = fmaf(dot, ss[f], acc);
        acc = fmaf(x / (1.0f + expf(-x)), bw[f], acc);
    }
#pragma unroll
    for (int off = 32; off > 0; off >>= 1) acc += __shfl_down(acc, off);
    if (lane == 0) out[row] = acc;
}

// ---------------------------------------------------------------------------
// ws layout (bytes)
#define WH0_OFF 0u
#define WL0_OFF (WH0_OFF + 147456u)      // 288*256*2
#define WH1_OFF (WL0_OFF + 147456u)
#define WL1_OFF (WH1_OFF + 1179648u)     // 2304*256*2
#define WH2_OFF (WL1_OFF + 1179648u)
#define WL2_OFF (WH2_OFF + 1179648u)
#define H0_OFF  (WL2_OFF + 1179648u)     // 32768*32*4
#define HA_OFF  (H0_OFF + 4194304u)      // 32768*256*4
#define HB_OFF  (HA_OFF + 33554432u)
// total = 76,316,672 B

extern "C" void kernel_launch(void* const* d_in, const int* in_sizes, int n_in,
                              void* d_out, int out_size, void* d_ws, size_t ws_size,
                              hipStream_t stream) {
    const float* x    = (const float*)d_in[0];
    const float* freq = (const float*)d_in[1];
    const float* bw0  = (const float*)d_in[2];
    const float* sw0  = (const float*)d_in[3];
    const float* ss0  = (const float*)d_in[4];
    const float* bw1  = (const float*)d_in[5];
    const float* sw1  = (const float*)d_in[6];
    const float* ss1  = (const float*)d_in[7];
    const float* bw2  = (const float*)d_in[8];
    const float* sw2  = (const float*)d_in[9];
    const float* ss2  = (const float*)d_in[10];
    const float* bw3  = (const float*)d_in[11];
    const float* sw3  = (const float*)d_in[12];
    const float* ss3  = (const float*)d_in[13];

    char* ws = (char*)d_ws;
    short* Wh0 = (short*)(ws + WH0_OFF);
    short* Wl0 = (short*)(ws + WL0_OFF);
    short* Wh1 = (short*)(ws + WH1_OFF);
    short* Wl1 = (short*)(ws + WL1_OFF);
    short* Wh2 = (short*)(ws + WH2_OFF);
    short* Wl2 = (short*)(ws + WL2_OFF);
    float* h0 = (float*)(ws + H0_OFF);
    float* hA = (float*)(ws + HA_OFF);
    float* hB = (float*)(ws + HB_OFF);
    float* outp = (float*)d_out;

    prep_kernel<<<288, 256, 0, stream>>>(bw0, sw0, ss0, Wh0, Wl0, 32);
    prep_kernel<<<2304, 256, 0, stream>>>(bw1, sw1, ss1, Wh1, Wl1, 256);
    prep_kernel<<<2304, 256, 0, stream>>>(bw2, sw2, ss2, Wh2, Wl2, 256);

    encode_kernel<<<(N_PTS + 255) / 256, 256, 0, stream>>>(x, freq, h0);

    layer_mfma<32><<<N_PTS / 128, 512, 0, stream>>>(h0, Wh0, Wl0, hA);
    layer_mfma<256><<<N_PTS / 128, 512, 0, stream>>>(hA, Wh1, Wl1, hB);
    layer_mfma<256><<<N_PTS / 128, 512, 0, stream>>>(hB, Wh2, Wl2, hA);

    layer3_kernel<<<(N_PTS * 64) / 256, 256, 0, stream>>>(hA, sw3, ss3, bw3, outp);
}

// Round 7
// 370.796 us; speedup vs baseline: 1.2125x; 1.2125x over previous
//
#include <hip/hip_runtime.h>
#include <math.h>
#include <stdint.h>

// ---------------------------------------------------------------------------
// KAN forward, split-bf16 MFMA version, round 10: broken acc chains.
//   Flow = R6 (best stable base): 512 thr / 8 waves / 128 rows, split-K chunk
//   parity, one __syncthreads per pair, LDS 128 KB double pair-buffer,
//   32x32x16. Builds at pair start (no build-pipelining: its +1% cost 32 VGPR
//   that we now spend on W-frag batching — R7 ran at 252/256 unified regs,
//   forcing the scheduler into 6-deep same-acc MFMA chains).
//   NEW: MFMA cluster is product-major over ct-groups of 4:
//     per kh, per group {0-3},{4-7}:
//       load wh[4] -> 4x mfma(Ah,wh,acc[i]) -> 4x mfma(Al,wh,acc[i])
//       load wl[4] -> 4x mfma(Ah,wl,acc[i])
//   Consecutive MFMAs hit different accumulators (3 independent MFMAs between
//   chain neighbors), hiding MFMA latency. Per-acc order unchanged
//   (AhWh -> AlWh -> AhWl per kh) => bitwise-identical results.
//   Augmented-K GEMM per layer: K = 9F (8 spline bases + 1 silu per feature).
//   W prefolded, split into bf16 hi/lo pair, staged via global_load_lds.
//   3-product split emulation: Ah*Wh + Al*Wh + Ah*Wl  (error ~2^-16 rel).
// ---------------------------------------------------------------------------

#define N_PTS 32768

using short8 = __attribute__((ext_vector_type(8))) short;
using f32x4  = __attribute__((ext_vector_type(4))) float;
using f32x16 = __attribute__((ext_vector_type(16))) float;

union Frag { short8 v; uint32_t u[4]; };

__device__ __forceinline__ uint32_t bf16rne(float f) {
    uint32_t u = __float_as_uint(f);
    return (u + 0x7FFFu + ((u >> 16) & 1u)) >> 16;
}
__device__ __forceinline__ float bf16tof(uint32_t h) { return __uint_as_float(h << 16); }

// pack bf16-trunc(x0) into lo16, bf16-trunc(x1) into hi16 — one v_perm_b32
__device__ __forceinline__ uint32_t pkhi(uint32_t x0, uint32_t x1) {
    return __builtin_amdgcn_perm(x1, x0, 0x07060302u);
}

// async global->LDS, 16B per lane (wave-uniform base + lane*16 semantics)
__device__ __forceinline__ void gld16(const void* g, void* lds) {
    __builtin_amdgcn_global_load_lds(
        (const __attribute__((address_space(1))) void*)(uintptr_t)g,
        (__attribute__((address_space(3))) void*)(uint32_t)(uintptr_t)lds,
        16, 0, 0);
}

// ---------------------------------------------------------------------------
// fast uniform cubic B-spline, trunc-split bf16 fragments.
// t = (x+2.2)/0.4 ; i = floor(t) ; slot j nonzero for j = i-3..i with value
// q_{i-j}.  Pair p (slots 2p,2p+1) selected from 5 packed candidates by i-2p.
__device__ __forceinline__ void build_basis_frag(float x, Frag& ah, Frag& al) {
    float t  = (x + 2.2f) * 2.5f;
    float fl = floorf(t);
    int   i  = (int)fl;
    float w  = t - fl;
    float w2 = w * w, w3 = w2 * w;
    const float s = 1.0f / 6.0f;
    float q0 = w3 * s;                                     // d == 0 (j == i)
    float q1 = (-3.f * w3 + 3.f * w2 + 3.f * w + 1.f) * s; // d == 1
    float q2 = (3.f * w3 - 6.f * w2 + 4.f) * s;            // d == 2
    float omw = 1.f - w;
    float q3 = omw * omw * omw * s;                        // d == 3
    uint32_t u0 = __float_as_uint(q0), u1 = __float_as_uint(q1);
    uint32_t u2 = __float_as_uint(q2), u3 = __float_as_uint(q3);
    // exact residual of the truncated head, then bf16-trunc via perm
    uint32_t r0 = __float_as_uint(q0 - __uint_as_float(u0 & 0xFFFF0000u));
    uint32_t r1 = __float_as_uint(q1 - __uint_as_float(u1 & 0xFFFF0000u));
    uint32_t r2 = __float_as_uint(q2 - __uint_as_float(u2 & 0xFFFF0000u));
    uint32_t r3 = __float_as_uint(q3 - __uint_as_float(u3 & 0xFFFF0000u));
    uint32_t PH0 = pkhi(u0, 0u), PH1 = pkhi(u1, u0), PH2 = pkhi(u2, u1),
             PH3 = pkhi(u3, u2), PH4 = pkhi(0u, u3);
    uint32_t PL0 = pkhi(r0, 0u), PL1 = pkhi(r1, r0), PL2 = pkhi(r2, r1),
             PL3 = pkhi(r3, r2), PL4 = pkhi(0u, r3);
#pragma unroll
    for (int p = 0; p < 4; ++p) {
        bool c0 = (i == 2 * p), c1 = (i == 2 * p + 1), c2 = (i == 2 * p + 2),
             c3 = (i == 2 * p + 3), c4 = (i == 2 * p + 4);
        ah.u[p] = c0 ? PH0 : c1 ? PH1 : c2 ? PH2 : c3 ? PH3 : c4 ? PH4 : 0u;
        al.u[p] = c0 ? PL0 : c1 ? PL1 : c2 ? PL2 : c3 ? PL3 : c4 ? PL4 : 0u;
    }
}

__device__ __forceinline__ void build_silu_frag(const float* __restrict__ xp, Frag& ah, Frag& al) {
    float4 a = *(const float4*)xp;
    float4 b = *(const float4*)(xp + 4);
    float xs[8] = {a.x, a.y, a.z, a.w, b.x, b.y, b.z, b.w};
#pragma unroll
    for (int p = 0; p < 4; ++p) {
        float x0 = xs[p * 2], x1 = xs[p * 2 + 1];
        float v0 = x0 / (1.f + __expf(-x0));
        float v1 = x1 / (1.f + __expf(-x1));
        uint32_t w0 = __float_as_uint(v0), w1 = __float_as_uint(v1);
        uint32_t l0 = __float_as_uint(v0 - __uint_as_float(w0 & 0xFFFF0000u));
        uint32_t l1 = __float_as_uint(v1 - __uint_as_float(w1 & 0xFFFF0000u));
        ah.u[p] = pkhi(w0, w1);
        al.u[p] = pkhi(l0, l1);
    }
}

// ---------------------------------------------------------------------------
__global__ void encode_kernel(const float* __restrict__ x,
                              const float* __restrict__ freq,
                              float* __restrict__ h0) {
    int n = blockIdx.x * blockDim.x + threadIdx.x;
    if (n >= N_PTS) return;
    float xv = x[n];
#pragma unroll
    for (int l = 0; l < 16; ++l) {
        float e = xv * freq[l];
        h0[n * 32 + l]      = sinf(e);
        h0[n * 32 + 16 + l] = cosf(e);
    }
}

// Fold sw*ss (k = f*8+j) and bw (k = 8F+f) into split-bf16 pair, layout
// Wh/Wl[(k>>3)][col][k&7] so fragment reads are ds_read_b128-contiguous and
// chunk staging (32 k x 256 cols = 16 KB) is flat-contiguous.
__global__ void prep_kernel(const float* __restrict__ bw,
                            const float* __restrict__ sw,
                            const float* __restrict__ ss,
                            short* __restrict__ Wh, short* __restrict__ Wl, int F) {
    int id = blockIdx.x * blockDim.x + threadIdx.x;
    int K = 9 * F;
    if (id >= K * 256) return;
    int col = id & 255;
    int k   = id >> 8;
    float wv;
    if (k < 8 * F) {
        int f = k >> 3, j = k & 7;
        wv = sw[(col * F + f) * 8 + j] * ss[col * F + f];
    } else {
        int f = k - 8 * F;
        wv = bw[col * F + f];
    }
    uint32_t hh = bf16rne(wv);
    uint32_t ll = bf16rne(wv - bf16tof(hh));
    size_t idx = ((size_t)(k >> 3) * 256 + col) * 8 + (k & 7);
    Wh[idx] = (short)hh;
    Wl[idx] = (short)ll;
}

// ---------------------------------------------------------------------------
// out(N,256) = Aug(h)(N,9F) @ W(9F,256), split-bf16 32x32x16 MFMA, split-K,
// chain-broken MFMA groups. Wave (rg, ks): 32 rows, chunks c with c%2==ks.
// A-frag layout (32x32x16): row = lane&31, k = (lane>>5)*8 + j.
// B-frag layout:            col = lane&31, k = (lane>>5)*8 + j.
// C/D layout:               col = lane&31, row = (reg&3)+8*(reg>>2)+4*(lane>>5).
template <int F>
__global__ __launch_bounds__(512, 2)
void layer_mfma(const float* __restrict__ hin,
                const short* __restrict__ Wh, const short* __restrict__ Wl,
                float* __restrict__ out) {
    constexpr int KBC = F / 4;         // basis chunks (8F/32)
    constexpr int KSC = F / 32;        // silu chunks
    constexpr int NC  = KBC + KSC;
    constexpr int NP  = (NC + 1) / 2;  // chunk pairs (last may be singleton)
    __shared__ short WB[2][2][2][8192];   // [pairbuf][cip][h/l][32k x 256col] = 128 KB

    const int tid  = threadIdx.x;
    const int wv   = tid >> 6;
    const int rg   = wv & 3;           // row-group 0..3
    const int ks   = wv >> 2;          // chunk parity 0..1
    const int lane = tid & 63;
    const int lc   = lane & 31;        // A row / B col within tile
    const int half = lane >> 5;        // k-subgroup
    const int row0 = blockIdx.x * 128;
    const int r    = row0 + rg * 32 + lc;   // this lane's A row
    const float* hrow = hin + (size_t)r * F;

    f32x16 acc[8];
#pragma unroll
    for (int a = 0; a < 8; ++a)
#pragma unroll
        for (int e = 0; e < 16; ++e) acc[a][e] = 0.f;

    auto stage_pair = [&](int p, int buf) {
#pragma unroll
        for (int cip = 0; cip < 2; ++cip) {
            int c = 2 * p + cip;
            if (c < NC) {
                const size_t gof = (size_t)c * 8192;
#pragma unroll
                for (int i = 0; i < 2; ++i) {
                    int e = tid * 8 + i * 4096;
                    gld16(Wh + gof + e, &WB[buf][cip][0][e]);
                    gld16(Wl + gof + e, &WB[buf][cip][1][e]);
                }
            }
        }
    };

    // stage pair 0 into buf 0
    stage_pair(0, 0);

    // preload x for my first chunk (c0 = ks, always a basis chunk):
    // feature = c*4 + kh*2 + half
    float xreg[2];
#pragma unroll
    for (int kh = 0; kh < 2; ++kh)
        xreg[kh] = hrow[ks * 4 + kh * 2 + half];
    __syncthreads();

    for (int p = 0; p < NP; ++p) {
        const int cur = p & 1;
        if (p + 1 < NP) stage_pair(p + 1, cur ^ 1);

        const int c = 2 * p + ks;      // my chunk this pair
        if (c < NC) {
            // ---- A fragments (registers), one per k-half ----
            Frag ah[2], al[2];
            if (c < KBC) {
                float x0 = xreg[0], x1 = xreg[1];
                if (c + 2 < KBC) {   // prefetch activations for my next chunk
#pragma unroll
                    for (int kh = 0; kh < 2; ++kh)
                        xreg[kh] = hrow[(c + 2) * 4 + kh * 2 + half];
                }
                build_basis_frag(x0, ah[0], al[0]);
                build_basis_frag(x1, ah[1], al[1]);
            } else {
                const int fb = (c - KBC) * 32 + half * 8;
#pragma unroll
                for (int kh = 0; kh < 2; ++kh)
                    build_silu_frag(&hrow[fb + kh * 16], ah[kh], al[kh]);
            }

            // ---- MFMA: product-major ct-groups of 4 (chain-broken) ----
            const short* WHp = WB[cur][ks][0];
            const short* WLp = WB[cur][ks][1];
#pragma unroll
            for (int kh = 0; kh < 2; ++kh) {
#pragma unroll
                for (int g = 0; g < 2; ++g) {
                    const int cb  = g * 4;
                    const int ob  = ((kh * 2 + half) * 256 + cb * 32 + lc) * 8;
                    Frag w0, w1, w2, w3;
                    w0.v = *(const short8*)&WHp[ob];
                    w1.v = *(const short8*)&WHp[ob + 256];
                    w2.v = *(const short8*)&WHp[ob + 512];
                    w3.v = *(const short8*)&WHp[ob + 768];
                    acc[cb + 0] = __builtin_amdgcn_mfma_f32_32x32x16_bf16(ah[kh].v, w0.v, acc[cb + 0], 0, 0, 0);
                    acc[cb + 1] = __builtin_amdgcn_mfma_f32_32x32x16_bf16(ah[kh].v, w1.v, acc[cb + 1], 0, 0, 0);
                    acc[cb + 2] = __builtin_amdgcn_mfma_f32_32x32x16_bf16(ah[kh].v, w2.v, acc[cb + 2], 0, 0, 0);
                    acc[cb + 3] = __builtin_amdgcn_mfma_f32_32x32x16_bf16(ah[kh].v, w3.v, acc[cb + 3], 0, 0, 0);
                    acc[cb + 0] = __builtin_amdgcn_mfma_f32_32x32x16_bf16(al[kh].v, w0.v, acc[cb + 0], 0, 0, 0);
                    acc[cb + 1] = __builtin_amdgcn_mfma_f32_32x32x16_bf16(al[kh].v, w1.v, acc[cb + 1], 0, 0, 0);
                    acc[cb + 2] = __builtin_amdgcn_mfma_f32_32x32x16_bf16(al[kh].v, w2.v, acc[cb + 2], 0, 0, 0);
                    acc[cb + 3] = __builtin_amdgcn_mfma_f32_32x32x16_bf16(al[kh].v, w3.v, acc[cb + 3], 0, 0, 0);
                    Frag v0, v1, v2, v3;
                    v0.v = *(const short8*)&WLp[ob];
                    v1.v = *(const short8*)&WLp[ob + 256];
                    v2.v = *(const short8*)&WLp[ob + 512];
                    v3.v = *(const short8*)&WLp[ob + 768];
                    acc[cb + 0] = __builtin_amdgcn_mfma_f32_32x32x16_bf16(ah[kh].v, v0.v, acc[cb + 0], 0, 0, 0);
                    acc[cb + 1] = __builtin_amdgcn_mfma_f32_32x32x16_bf16(ah[kh].v, v1.v, acc[cb + 1], 0, 0, 0);
                    acc[cb + 2] = __builtin_amdgcn_mfma_f32_32x32x16_bf16(ah[kh].v, v2.v, acc[cb + 2], 0, 0, 0);
                    acc[cb + 3] = __builtin_amdgcn_mfma_f32_32x32x16_bf16(ah[kh].v, v3.v, acc[cb + 3], 0, 0, 0);
                }
            }
        }
        __syncthreads();
    }

    // ---- cross-ks reduction via LDS (WB reused as 32K-float scratch) ----
    // Tile (rg, ks, cti) = 1024 floats at ((rg*2+ks)*4+cti)*1024; within:
    // e4*256 + lane*4 (contiguous 16B/lane — conflict-free b128 pattern).
    // Wave (rg, ks) writes its partials for the OTHER half's col-tiles, then
    // reads partner's partials for its OWN half, adds, stores to global.
    float* red = (float*)WB;
    {
        float* wp = red + (size_t)((rg * 2 + ks) * 4) * 1024 + lane * 4;
        if (ks == 0) {
#pragma unroll
            for (int cti = 0; cti < 4; ++cti)
#pragma unroll
                for (int e4 = 0; e4 < 4; ++e4) {
                    f32x4 v = {acc[4 + cti][e4 * 4 + 0], acc[4 + cti][e4 * 4 + 1],
                               acc[4 + cti][e4 * 4 + 2], acc[4 + cti][e4 * 4 + 3]};
                    *(f32x4*)(wp + cti * 1024 + e4 * 256) = v;
                }
        } else {
#pragma unroll
            for (int cti = 0; cti < 4; ++cti)
#pragma unroll
                for (int e4 = 0; e4 < 4; ++e4) {
                    f32x4 v = {acc[cti][e4 * 4 + 0], acc[cti][e4 * 4 + 1],
                               acc[cti][e4 * 4 + 2], acc[cti][e4 * 4 + 3]};
                    *(f32x4*)(wp + cti * 1024 + e4 * 256) = v;
                }
        }
    }
    __syncthreads();
    {
        const float* rp = red + (size_t)((rg * 2 + (1 - ks)) * 4) * 1024 + lane * 4;
        if (ks == 0) {
#pragma unroll
            for (int cti = 0; cti < 4; ++cti) {
                const int colg = cti * 32 + lc;
#pragma unroll
                for (int e4 = 0; e4 < 4; ++e4) {
                    f32x4 v = *(const f32x4*)(rp + cti * 1024 + e4 * 256);
#pragma unroll
                    for (int j = 0; j < 4; ++j) {
                        const int rgi  = e4 * 4 + j;
                        const int rowg = row0 + rg * 32 + (rgi & 3) + 8 * (rgi >> 2) + 4 * half;
                        out[(size_t)rowg * 256 + colg] = acc[cti][rgi] + v[j];
                    }
                }
            }
        } else {
#pragma unroll
            for (int cti = 0; cti < 4; ++cti) {
                const int colg = (4 + cti) * 32 + lc;
#pragma unroll
                for (int e4 = 0; e4 < 4; ++e4) {
                    f32x4 v = *(const f32x4*)(rp + cti * 1024 + e4 * 256);
#pragma unroll
                    for (int j = 0; j < 4; ++j) {
                        const int rgi  = e4 * 4 + j;
                        const int rowg = row0 + rg * 32 + (rgi & 3) + 8 * (rgi >> 2) + 4 * half;
                        out[(size_t)rowg * 256 + colg] = acc[4 + cti][rgi] + v[j];
                    }
                }
            }
        }
    }
}

// ---------------------------------------------------------------------------
// Final layer (n_out=1), fp32 wave-reduce.
__device__ __forceinline__ float knotf(int j) { return (float)(j - 3) * 0.4f - 1.0f; }

__device__ __forceinline__ void spline8(float x, float b[8]) {
    float b0[11];
#pragma unroll
    for (int j = 0; j < 11; ++j)
        b0[j] = (x >= knotf(j) && x < knotf(j + 1)) ? 1.0f : 0.0f;
    float b1[10];
#pragma unroll
    for (int j = 0; j < 10; ++j)
        b1[j] = (x - knotf(j)) * (1.0f / (knotf(j + 1) - knotf(j))) * b0[j]
              + (knotf(j + 2) - x) * (1.0f / (knotf(j + 2) - knotf(j + 1))) * b0[j + 1];
    float b2[9];
#pragma unroll
    for (int j = 0; j < 9; ++j)
        b2[j] = (x - knotf(j)) * (1.0f / (knotf(j + 2) - knotf(j))) * b1[j]
              + (knotf(j + 3) - x) * (1.0f / (knotf(j + 3) - knotf(j + 1))) * b1[j + 1];
#pragma unroll
    for (int j = 0; j < 8; ++j)
        b[j]  = (x - knotf(j)) * (1.0f / (knotf(j + 3) - knotf(j))) * b2[j]
              + (knotf(j + 4) - x) * (1.0f / (knotf(j + 4) - knotf(j + 1))) * b2[j + 1];
}

__global__ void layer3_kernel(const float* __restrict__ hin,
                              const float* __restrict__ sw,
                              const float* __restrict__ ss,
                              const float* __restrict__ bw,
                              float* __restrict__ out) {
    int gid  = blockIdx.x * blockDim.x + threadIdx.x;
    int row  = gid >> 6;
    int lane = gid & 63;
    if (row >= N_PTS) return;
    float acc = 0.0f;
#pragma unroll
    for (int it = 0; it < 4; ++it) {
        int f = lane + it * 64;
        float x = hin[(size_t)row * 256 + f];
        float b[8];
        spline8(x, b);
        float dot = 0.0f;
#pragma unroll
        for (int j = 0; j < 8; ++j) dot = fmaf(b[j], sw[f * 8 + j], dot);
        acc = fmaf(dot, ss[f], acc);
        acc = fmaf(x / (1.0f + expf(-x)), bw[f], acc);
    }
#pragma unroll
    for (int off = 32; off > 0; off >>= 1) acc += __shfl_down(acc, off);
    if (lane == 0) out[row] = acc;
}

// ---------------------------------------------------------------------------
// ws layout (bytes)
#define WH0_OFF 0u
#define WL0_OFF (WH0_OFF + 147456u)      // 288*256*2
#define WH1_OFF (WL0_OFF + 147456u)
#define WL1_OFF (WH1_OFF + 1179648u)     // 2304*256*2
#define WH2_OFF (WL1_OFF + 1179648u)
#define WL2_OFF (WH2_OFF + 1179648u)
#define H0_OFF  (WL2_OFF + 1179648u)     // 32768*32*4
#define HA_OFF  (H0_OFF + 4194304u)      // 32768*256*4
#define HB_OFF  (HA_OFF + 33554432u)
// total = 76,316,672 B

extern "C" void kernel_launch(void* const* d_in, const int* in_sizes, int n_in,
                              void* d_out, int out_size, void* d_ws, size_t ws_size,
                              hipStream_t stream) {
    const float* x    = (const float*)d_in[0];
    const float* freq = (const float*)d_in[1];
    const float* bw0  = (const float*)d_in[2];
    const float* sw0  = (const float*)d_in[3];
    const float* ss0  = (const float*)d_in[4];
    const float* bw1  = (const float*)d_in[5];
    const float* sw1  = (const float*)d_in[6];
    const float* ss1  = (const float*)d_in[7];
    const float* bw2  = (const float*)d_in[8];
    const float* sw2  = (const float*)d_in[9];
    const float* ss2  = (const float*)d_in[10];
    const float* bw3  = (const float*)d_in[11];
    const float* sw3  = (const float*)d_in[12];
    const float* ss3  = (const float*)d_in[13];

    char* ws = (char*)d_ws;
    short* Wh0 = (short*)(ws + WH0_OFF);
    short* Wl0 = (short*)(ws + WL0_OFF);
    short* Wh1 = (short*)(ws + WH1_OFF);
    short* Wl1 = (short*)(ws + WL1_OFF);
    short* Wh2 = (short*)(ws + WH2_OFF);
    short* Wl2 = (short*)(ws + WL2_OFF);
    float* h0 = (float*)(ws + H0_OFF);
    float* hA = (float*)(ws + HA_OFF);
    float* hB = (float*)(ws + HB_OFF);
    float* outp = (float*)d_out;

    prep_kernel<<<288, 256, 0, stream>>>(bw0, sw0, ss0, Wh0, Wl0, 32);
    prep_kernel<<<2304, 256, 0, stream>>>(bw1, sw1, ss1, Wh1, Wl1, 256);
    prep_kernel<<<2304, 256, 0, stream>>>(bw2, sw2, ss2, Wh2, Wl2, 256);

    encode_kernel<<<(N_PTS + 255) / 256, 256, 0, stream>>>(x, freq, h0);

    layer_mfma<32><<<N_PTS / 128, 512, 0, stream>>>(h0, Wh0, Wl0, hA);
    layer_mfma<256><<<N_PTS / 128, 512, 0, stream>>>(hA, Wh1, Wl1, hB);
    layer_mfma<256><<<N_PTS / 128, 512, 0, stream>>>(hB, Wh2, Wl2, hA);

    layer3_kernel<<<(N_PTS * 64) / 256, 256, 0, stream>>>(hA, sw3, ss3, bw3, outp);
}